// Round 5
// baseline (360.531 us; speedup 1.0000x reference)
//
#include <hip/hip_runtime.h>
#include <hip/hip_bf16.h>

// Problem constants (from setup_inputs): x[B=32, N=8192, F=256] fp32, k=1024.
#define B_DIM 32
#define N_DIM 8192
#define F_DIM 256
#define K_DIM 1024
#define CHUNK 4096            // rows per phase-1 block
#define CHUNKS_PER_B 2

// Monotonic float32 -> uint32 transform (total order; inputs are normals, no NaN).
__device__ __forceinline__ unsigned int f32_ord(float v) {
    unsigned int u = __float_as_uint(v);
    return (u & 0x80000000u) ? ~u : (u | 0x80000000u);
}

// ---------------------------------------------------------------------------
// Phase 1: B*2 blocks x 1024 threads, 32 KB LDS. Each block reduces 4096 rows
// to its sorted-descending top-1024 (any element ranked >=1024 inside its own
// chunk cannot be in the global top-1024).
//   Stage A: sort quarters q0..q3 in directions D,A,D,A      (55 passes)
//   Stage B: max-combine q0/q1 -> K[0..1024) bitonic,
//            q2/q3 -> K[2048..3072) bitonic                  (1 pass)
//   Stage C: bitonic-merge those two, desc / asc             (10 passes)
//   Stage D: max-combine (desc,asc) pair -> K[0..1024)       (1 pass)
//   Stage E: bitonic-merge descending                        (10 passes)
// Key = (ord(value) << 32) | (N-1-row): u64-desc == value-desc, ties -> lowest
// row index first (lax.top_k semantics). All keys unique.
// ---------------------------------------------------------------------------
__global__ __launch_bounds__(1024)
void sort_chunks_kernel(const float* __restrict__ x,
                        unsigned long long* __restrict__ runs) {
    __shared__ unsigned long long K[CHUNK];  // 32 KB

    const int blk = blockIdx.x;       // b * 2 + c
    const int b   = blk >> 1;
    const int c   = blk & 1;
    const float* xcol = x + (size_t)b * N_DIM * F_DIM + (F_DIM - 1);
    const int base = c * CHUNK;

    for (int i = threadIdx.x; i < CHUNK; i += 1024) {
        int row = base + i;
        float v = xcol[(size_t)row * F_DIM];
        K[i] = ((unsigned long long)f32_ord(v) << 32) |
               (unsigned int)(N_DIM - 1 - row);
    }
    __syncthreads();

    // Stage A: four independent 1024-sorts, alternating desc/asc.
    for (unsigned int kk = 2; kk <= 1024; kk <<= 1) {
        for (unsigned int jj = kk >> 1; jj > 0; jj >>= 1) {
            for (unsigned int p = threadIdx.x; p < 2048; p += 1024) {
                unsigned int q  = p >> 9;           // quarter 0..3
                unsigned int lp = p & 511u;
                unsigned int il = ((lp & ~(jj - 1)) << 1) | (lp & (jj - 1));
                unsigned int i  = (q << 10) + il;
                unsigned int j  = i | jj;
                bool desc = (((il & kk) == 0) != (bool)(q & 1));
                unsigned long long a  = K[i];
                unsigned long long bb = K[j];
                if (desc ? (a < bb) : (a > bb)) { K[i] = bb; K[j] = a; }
            }
            __syncthreads();
        }
    }

    // Stage B: C[i] = max(A_desc[i], B_asc[i]) == exact top-1024 of pair,
    // valley-bitonic result. 2048 work items: (q0,q1)@0 and (q2,q3)@2048.
    for (unsigned int t = threadIdx.x; t < 2048; t += 1024) {
        unsigned int h = t >> 10, i = t & 1023u;
        unsigned int a = h << 11;                    // 0 or 2048
        unsigned long long bv = K[a + 1024u + i];
        if (bv > K[a + i]) K[a + i] = bv;
    }
    __syncthreads();

    // Stage C: merge K[0..1024) descending, K[2048..3072) ascending.
    for (unsigned int jj = 512; jj > 0; jj >>= 1) {
        unsigned int p  = threadIdx.x;              // 1024 pairs
        unsigned int h  = p >> 9;
        unsigned int lp = p & 511u;
        unsigned int il = ((lp & ~(jj - 1)) << 1) | (lp & (jj - 1));
        unsigned int i  = (h << 11) + il;
        unsigned int j  = i | jj;
        bool desc = (h == 0);
        unsigned long long a  = K[i];
        unsigned long long bb = K[j];
        if (desc ? (a < bb) : (a > bb)) { K[i] = bb; K[j] = a; }
        __syncthreads();
    }

    // Stage D: combine (desc @0, asc @2048): C[i] = max(K[i], K[2048+i]).
    if (threadIdx.x < 1024) {
        unsigned int i = threadIdx.x;
        unsigned long long bv = K[2048u + i];
        if (bv > K[i]) K[i] = bv;
    }
    __syncthreads();

    // Stage E: bitonic merge descending on K[0..1024).
    for (unsigned int jj = 512; jj > 0; jj >>= 1) {
        if (threadIdx.x < 512) {
            unsigned int lp = threadIdx.x;
            unsigned int i = ((lp & ~(jj - 1)) << 1) | (lp & (jj - 1));
            unsigned int j = i | jj;
            unsigned long long a  = K[i];
            unsigned long long bb = K[j];
            if (a < bb) { K[i] = bb; K[j] = a; }
        }
        __syncthreads();
    }

    // Store sorted run (16 B / thread).
    if (threadIdx.x < 512) {
        ulonglong2* dst = (ulonglong2*)(runs + (size_t)blk * K_DIM);
        const ulonglong2* srcv = (const ulonglong2*)K;
        dst[threadIdx.x] = srcv[threadIdx.x];
    }
}

// ---------------------------------------------------------------------------
// Phase 2: one block per batch, 512 threads, 16 KB LDS. Merge the 2 sorted
// runs: C[i] = max(A[i], A[2047-i]) (exact top-1024, bitonic), then 10-pass
// bitonic merge descending. 12 barriers total.
// ---------------------------------------------------------------------------
__global__ __launch_bounds__(512)
void merge_topk_kernel(const unsigned long long* __restrict__ runs,
                       int* __restrict__ idx_out) {
    __shared__ unsigned long long A[2 * K_DIM];  // 16 KB

    const int b = blockIdx.x;
    const ulonglong2* src = (const ulonglong2*)(runs + (size_t)b * 2 * K_DIM);
    ulonglong2* Av = (ulonglong2*)A;
    for (unsigned int i = threadIdx.x; i < K_DIM; i += 512) Av[i] = src[i];
    __syncthreads();

    // Top-1024 of union: A[1024..2048) desc, reversed = asc.
    // Writes [0,1024), reads [1024,2048) -- disjoint, no hazard.
    for (unsigned int i = threadIdx.x; i < K_DIM; i += 512) {
        unsigned long long bv = A[2047u - i];
        if (bv > A[i]) A[i] = bv;
    }
    __syncthreads();

    for (unsigned int jj = 512; jj > 0; jj >>= 1) {
        unsigned int lp = threadIdx.x;              // 512 pairs
        unsigned int i = ((lp & ~(jj - 1)) << 1) | (lp & (jj - 1));
        unsigned int j = i | jj;
        unsigned long long a = A[i];
        unsigned long long c = A[j];
        if (a < c) { A[i] = c; A[j] = a; }
        __syncthreads();
    }

    for (unsigned int i = threadIdx.x; i < K_DIM; i += 512) {
        unsigned int low = (unsigned int)(A[i] & 0xFFFFFFFFu);
        idx_out[b * K_DIM + i] = (int)(N_DIM - 1 - low);
    }
}

// ---------------------------------------------------------------------------
// Gather: out[b, j, :] = x[b, idx[b*K + j], :].
// One float4 per thread; each 64-lane wave covers exactly one 1 KB row.
// ---------------------------------------------------------------------------
__global__ __launch_bounds__(256)
void gather_rows_kernel(const float* __restrict__ x,
                        const int* __restrict__ idx,
                        float* __restrict__ out) {
    size_t gid = (size_t)blockIdx.x * blockDim.x + threadIdx.x; // per float4
    int f4     = (int)(gid & (F_DIM / 4 - 1));   // 0..63
    size_t row = gid >> 6;                       // b*K + j
    int b      = (int)(row >> 10);               // / K_DIM
    int src    = idx[row];                       // wave-uniform -> broadcast

    const float4* src_ptr =
        (const float4*)(x + ((size_t)b * N_DIM + (size_t)src) * F_DIM) + f4;
    ((float4*)out)[gid] = *src_ptr;
}

extern "C" void kernel_launch(void* const* d_in, const int* in_sizes, int n_in,
                              void* d_out, int out_size, void* d_ws, size_t ws_size,
                              hipStream_t stream) {
    const float* x = (const float*)d_in[0];
    float* out = (float*)d_out;

    unsigned long long* runs = (unsigned long long*)d_ws;                    // 512 KB
    int* idx_ws = (int*)((char*)d_ws + (size_t)B_DIM * CHUNKS_PER_B * K_DIM * 8);

    sort_chunks_kernel<<<B_DIM * CHUNKS_PER_B, 1024, 0, stream>>>(x, runs);
    merge_topk_kernel<<<B_DIM, 512, 0, stream>>>(runs, idx_ws);

    const size_t total_f4 = (size_t)B_DIM * K_DIM * F_DIM / 4;  // 2,097,152
    gather_rows_kernel<<<(int)(total_f4 / 256), 256, 0, stream>>>(x, idx_ws, out);
}